// Round 10
// baseline (74.746 us; speedup 1.0000x reference)
//
#include <hip/hip_runtime.h>

#define CC 7
#define NN 32768
#define NCH 161
#define SPAN 512          // n per workgroup (512 threads, 8 waves)
#define W    520          // positions per coord row: p <-> n = N0 - 2 + p
// Lane tl, chunk h in {0,1}: owns n = N0 + 256h + 4tl .. +3;  window start p0 = 4tl + 256h.
// plane layout: n1 0-6 | n2 7-13 | cross1 14-20 | cross2 21-27 | adx1 28-34 |
//               adx2 35-41 | dirs 42-48 | d 49-97 | dd 98-146 | lead1 147-153 | lead2 154-160

typedef float vfloat4 __attribute__((ext_vector_type(4)));

__device__ __forceinline__ void stnt4(float* p, float4 v) {
    vfloat4 w = {v.x, v.y, v.z, v.w};
    __builtin_nontemporal_store(w, (vfloat4*)p);
}
__device__ __forceinline__ float frcp(float x) { return __builtin_amdgcn_rcpf(x); }
__device__ __forceinline__ float fsq(float x)  { return __builtin_amdgcn_sqrtf(x); }

// phase 3 pairs, j-major index pp = j*7 + i, unrolled over [LO, HI)
template <int LO, int HI>
__device__ __forceinline__ void phase3(const float (*S)[2][W], float* ob,
                                       int tl, int N0) {
#pragma unroll
    for (int pp = LO; pp < HI; ++pp) {
        const int j = pp / 7;
        const int i = pp % 7;
        int c1 = j - i - 1;
        c1 = (c1 < 0) ? c1 + 7 : c1;
        const int pair = i * 7 + j;
        float4 od[2], odd[2];
#pragma unroll
        for (int h = 0; h < 2; ++h) {
            const int p0 = 4 * tl + 256 * h;
            float4 BX0 = *(const float4*)&S[CC + j][0][p0];
            float4 BX1 = *(const float4*)&S[CC + j][0][p0 + 4];
            float4 BY0 = *(const float4*)&S[CC + j][1][p0];
            float4 BY1 = *(const float4*)&S[CC + j][1][p0 + 4];
            float4 AX0 = *(const float4*)&S[c1][0][p0];
            float4 AX1 = *(const float4*)&S[c1][0][p0 + 4];
            float4 AY0 = *(const float4*)&S[c1][1][p0];
            float4 AY1 = *(const float4*)&S[c1][1][p0 + 4];
            float w1x[5] = {AX0.z, AX0.w, AX1.x, AX1.y, AX1.z};
            float w1y[5] = {AY0.z, AY0.w, AY1.x, AY1.y, AY1.z};
            float w2x[5] = {BX0.z, BX0.w, BX1.x, BX1.y, BX1.z};
            float w2y[5] = {BY0.z, BY0.w, BY1.x, BY1.y, BY1.z};
            float d[5];
#pragma unroll
            for (int p = 0; p < 5; ++p) {
                float ddx = w1x[p] - w2x[p] + 1e-6f;
                float ddy = w1y[p] - w2y[p] + 1e-6f;
                d[p] = fsq(ddx * ddx + ddy * ddy);
            }
            const bool lastpt = (N0 + 256 * h + 4 * tl + 4 == NN);
            float dd3 = lastpt ? -d[3] : d[4] - d[3];
            od[h]  = make_float4(d[0], d[1], d[2], d[3]);
            odd[h] = make_float4(d[1] - d[0], d[2] - d[1], d[3] - d[2], dd3);
        }
        stnt4(ob + (size_t)(49 + pair) * NN,       od[0]);
        stnt4(ob + (size_t)(49 + pair) * NN + 256, od[1]);
        stnt4(ob + (size_t)(98 + pair) * NN,       odd[0]);
        stnt4(ob + (size_t)(98 + pair) * NN + 256, odd[1]);
    }
}

__global__ __launch_bounds__(512) void feat_kernel(const float* __restrict__ x,
                                                   float* __restrict__ out) {
    __shared__ float S[2 * CC][2][W];          // [channel][coord x/y][pos]  57 KB
    const int t  = threadIdx.x;
    const int N0 = blockIdx.x * SPAN;
    const int b  = blockIdx.y;

    const float* xb = x + (size_t)b * (2 * CC) * NN * 2;

    // ---- stage: global float2 AoS -> LDS SoA (x-row, y-row per channel) ----
    for (int idx = t; idx < 2 * CC * (W / 2); idx += 512) {
        int ch = idx / (W / 2);
        int m  = idx - ch * (W / 2);
        int g0 = N0 - 2 + 2 * m;               // global n of first of 2 points
        const float* p = xb + (size_t)ch * NN * 2;
        float4 v;
        if (g0 >= 0 && g0 + 1 < NN) {
            v = *(const float4*)(p + 2 * g0);
        } else {
            int ga = g0     < 0 ? 0 : (g0     > NN - 1 ? NN - 1 : g0);
            int gb = g0 + 1 < 0 ? 0 : (g0 + 1 > NN - 1 ? NN - 1 : g0 + 1);
            float2 va = *(const float2*)(p + 2 * ga);
            float2 vb = *(const float2*)(p + 2 * gb);
            v = make_float4(va.x, va.y, vb.x, vb.y);
        }
        *(float2*)&S[ch][0][2 * m] = make_float2(v.x, v.z);
        *(float2*)&S[ch][1][2 * m] = make_float2(v.y, v.w);
    }
    __syncthreads();

    const int wg = t >> 6;                     // wave-group 0..7
    const int tl = t & 63;
    float* ob = out + (size_t)b * NCH * NN + N0 + 4 * tl;

    // ---- phase 1: n / cross / adx; channels wg and wg+8 ----
#pragma unroll
    for (int it = 0; it < 2; ++it) {
        const int ch = wg + 8 * it;
        if (ch < 14) {
            float4 on[2], oc[2], oa[2];
#pragma unroll
            for (int h = 0; h < 2; ++h) {
                const int p0 = 4 * tl + 256 * h;
                float4 X0 = *(const float4*)&S[ch][0][p0];
                float4 X1 = *(const float4*)&S[ch][0][p0 + 4];
                float4 Y0 = *(const float4*)&S[ch][1][p0];
                float4 Y1 = *(const float4*)&S[ch][1][p0 + 4];
                float wx[6] = {X0.x, X0.y, X0.z, X0.w, X1.x, X1.y};
                float wy[6] = {Y0.x, Y0.y, Y0.z, Y0.w, Y1.x, Y1.y};
                float dx[5], dy[5], nr[5];
#pragma unroll
                for (int m = 0; m < 5; ++m) {
                    dx[m] = wx[m + 1] - wx[m];
                    dy[m] = wy[m + 1] - wy[m];
                    nr[m] = fsq(dx[m] * dx[m] + dy[m] * dy[m]);
                }
                float* vn = &on[h].x; float* vc = &oc[h].x; float* va = &oa[h].x;
#pragma unroll
                for (int k = 0; k < 4; ++k) {
                    vn[k] = nr[k + 1];
                    vc[k] = dx[k + 1] * (dy[k + 1] - dy[k]) - dy[k + 1] * (dx[k + 1] - dx[k]);
                    va[k] = (dx[k + 1] * dx[k] + dy[k + 1] * dy[k]) * frcp(nr[k + 1] * nr[k] + 1e-4f);
                }
            }
            stnt4(ob + (size_t)(ch) * NN,            on[0]);
            stnt4(ob + (size_t)(ch) * NN + 256,      on[1]);
            stnt4(ob + (size_t)(14 + ch) * NN,       oc[0]);
            stnt4(ob + (size_t)(14 + ch) * NN + 256, oc[1]);
            stnt4(ob + (size_t)(28 + ch) * NN,       oa[0]);
            stnt4(ob + (size_t)(28 + ch) * NN + 256, oa[1]);
        }
    }

    // ---- phase 2: dirs / lead1 / lead2; cpair c = wg-1 (wg 1..7) ----
    if (wg > 0) {
        const int c = wg - 1;
        float4 od[2], ol1[2], ol2[2];
#pragma unroll
        for (int h = 0; h < 2; ++h) {
            const int p0 = 4 * tl + 256 * h;
            float4 AX0 = *(const float4*)&S[c][0][p0];
            float4 AX1 = *(const float4*)&S[c][0][p0 + 4];
            float4 AY0 = *(const float4*)&S[c][1][p0];
            float4 AY1 = *(const float4*)&S[c][1][p0 + 4];
            float4 BX0 = *(const float4*)&S[c + CC][0][p0];
            float4 BX1 = *(const float4*)&S[c + CC][0][p0 + 4];
            float4 BY0 = *(const float4*)&S[c + CC][1][p0];
            float4 BY1 = *(const float4*)&S[c + CC][1][p0 + 4];
            float w1x[5] = {AX0.y, AX0.z, AX0.w, AX1.x, AX1.y};
            float w1y[5] = {AY0.y, AY0.z, AY0.w, AY1.x, AY1.y};
            float w2x[5] = {BX0.y, BX0.z, BX0.w, BX1.x, BX1.y};
            float w2y[5] = {BY0.y, BY0.z, BY0.w, BY1.x, BY1.y};
            float* vd = &od[h].x; float* v1 = &ol1[h].x; float* v2 = &ol2[h].x;
#pragma unroll
            for (int k = 0; k < 4; ++k) {
                float d1x = w1x[k + 1] - w1x[k], d1y = w1y[k + 1] - w1y[k];
                float d2x = w2x[k + 1] - w2x[k], d2y = w2y[k + 1] - w2y[k];
                float n1 = fsq(d1x * d1x + d1y * d1y);
                float n2 = fsq(d2x * d2x + d2y * d2y);
                float rx = w1x[k + 1] - w2x[k + 1], ry = w1y[k + 1] - w2y[k + 1];
                float nr = fsq(rx * rx + ry * ry);
                vd[k] = (d1x * d2x + d1y * d2y) * frcp(n1 * n2 + 1e-6f);
                v1[k] = (d1x * rx + d1y * ry) * frcp(n1 * nr + 1e-6f);
                v2[k] = -(d2x * rx + d2y * ry) * frcp(n2 * nr + 1e-6f);
            }
        }
        stnt4(ob + (size_t)(42 + c) * NN,        od[0]);
        stnt4(ob + (size_t)(42 + c) * NN + 256,  od[1]);
        stnt4(ob + (size_t)(147 + c) * NN,       ol1[0]);
        stnt4(ob + (size_t)(147 + c) * NN + 256, ol1[1]);
        stnt4(ob + (size_t)(154 + c) * NN,       ol2[0]);
        stnt4(ob + (size_t)(154 + c) * NN + 256, ol2[1]);
    }

    // ---- phase 3: d / dd; 49 pairs j-major, split {7,6,6,6,6,6,6,6} ----
    switch (wg) {
        case 0: phase3<0, 7>(S, ob, tl, N0); break;
        case 1: phase3<7, 13>(S, ob, tl, N0); break;
        case 2: phase3<13, 19>(S, ob, tl, N0); break;
        case 3: phase3<19, 25>(S, ob, tl, N0); break;
        case 4: phase3<25, 31>(S, ob, tl, N0); break;
        case 5: phase3<31, 37>(S, ob, tl, N0); break;
        case 6: phase3<37, 43>(S, ob, tl, N0); break;
        default: phase3<43, 49>(S, ob, tl, N0); break;
    }
}

extern "C" void kernel_launch(void* const* d_in, const int* in_sizes, int n_in,
                              void* d_out, int out_size, void* d_ws, size_t ws_size,
                              hipStream_t stream) {
    const float* x = (const float*)d_in[0];
    float* out = (float*)d_out;
    dim3 grid(NN / SPAN, 16);
    feat_kernel<<<grid, 512, 0, stream>>>(x, out);
}

// Round 11
// 67.985 us; speedup vs baseline: 1.0995x; 1.0995x over previous
//
#include <hip/hip_runtime.h>

#define CC 7
#define NN 32768
#define NCH 161
#define SPAN 256          // n per workgroup
#define W    264          // floats per coord row: pos2 window [N0-2 .. N0+261]
// pos p in row  <->  n = N0 - 2 + p.  Lane tl owns n = N0+4tl .. N0+4tl+3 (p0 = 4tl).
// plane layout: n1 0-6 | n2 7-13 | cross1 14-20 | cross2 21-27 | adx1 28-34 |
//               adx2 35-41 | dirs 42-48 | d 49-97 | dd 98-146 | lead1 147-153 | lead2 154-160

typedef float vfloat4 __attribute__((ext_vector_type(4)));

__device__ __forceinline__ void stnt4(float* p, float4 v) {
    vfloat4 w = {v.x, v.y, v.z, v.w};
    __builtin_nontemporal_store(w, (vfloat4*)p);
}
__device__ __forceinline__ float frcp(float x) { return __builtin_amdgcn_rcpf(x); }
__device__ __forceinline__ float fsq(float x)  { return __builtin_amdgcn_sqrtf(x); }

__global__ __launch_bounds__(256) void feat_kernel(const float* __restrict__ x,
                                                   float* __restrict__ out) {
    __shared__ float S[2 * CC][2][W];          // [channel][coord x/y][pos]
    const int t  = threadIdx.x;
    const int N0 = blockIdx.x * SPAN;
    const int b  = blockIdx.y;

    const float* xb = x + (size_t)b * (2 * CC) * NN * 2;

    // ---- stage: global float2 AoS -> LDS SoA (x-row, y-row per channel) ----
    for (int idx = t; idx < 2 * CC * (W / 2); idx += 256) {
        int ch = idx / (W / 2);
        int m  = idx - ch * (W / 2);
        int g0 = N0 - 2 + 2 * m;               // global n of first of 2 points
        const float* p = xb + (size_t)ch * NN * 2;
        float4 v;
        if (g0 >= 0 && g0 + 1 < NN) {
            v = *(const float4*)(p + 2 * g0);
        } else {
            int ga = g0     < 0 ? 0 : (g0     > NN - 1 ? NN - 1 : g0);
            int gb = g0 + 1 < 0 ? 0 : (g0 + 1 > NN - 1 ? NN - 1 : g0 + 1);
            float2 va = *(const float2*)(p + 2 * ga);
            float2 vb = *(const float2*)(p + 2 * gb);
            v = make_float4(va.x, va.y, vb.x, vb.y);
        }
        *(float2*)&S[ch][0][2 * m] = make_float2(v.x, v.z);
        *(float2*)&S[ch][1][2 * m] = make_float2(v.y, v.w);
    }
    __syncthreads();

    const int wg = t >> 6;                     // wave-group 0..3
    const int tl = t & 63;
    const int p0 = 4 * tl;
    float* ob = out + (size_t)b * NCH * NN + N0 + 4 * tl;

    // ---- phase 1: n / cross / adx for 14 channels ----
#pragma unroll
    for (int it = 0; it < 4; ++it) {
        const int ch = it * 4 + wg;
        if (ch < 14) {
            float4 X0 = *(const float4*)&S[ch][0][p0];
            float4 X1 = *(const float4*)&S[ch][0][p0 + 4];
            float4 Y0 = *(const float4*)&S[ch][1][p0];
            float4 Y1 = *(const float4*)&S[ch][1][p0 + 4];
            float wx[6] = {X0.x, X0.y, X0.z, X0.w, X1.x, X1.y};
            float wy[6] = {Y0.x, Y0.y, Y0.z, Y0.w, Y1.x, Y1.y};
            float dx[5], dy[5], nr[5];
#pragma unroll
            for (int m = 0; m < 5; ++m) {
                dx[m] = wx[m + 1] - wx[m];
                dy[m] = wy[m + 1] - wy[m];
                nr[m] = fsq(dx[m] * dx[m] + dy[m] * dy[m]);
            }
            float4 on, oc, oa;
            float* vn = &on.x; float* vc = &oc.x; float* va = &oa.x;
#pragma unroll
            for (int k = 0; k < 4; ++k) {
                vn[k] = nr[k + 1];
                vc[k] = dx[k + 1] * (dy[k + 1] - dy[k]) - dy[k + 1] * (dx[k + 1] - dx[k]);
                va[k] = (dx[k + 1] * dx[k] + dy[k + 1] * dy[k]) * frcp(nr[k + 1] * nr[k] + 1e-4f);
            }
            stnt4(ob + (size_t)(ch) * NN,      on);
            stnt4(ob + (size_t)(14 + ch) * NN, oc);
            stnt4(ob + (size_t)(28 + ch) * NN, oa);
        }
    }

    // ---- phase 2: dirs / lead1 / lead2 ----
#pragma unroll
    for (int it = 0; it < 2; ++it) {
        const int c = it * 4 + wg;
        if (c < 7) {
            float4 AX0 = *(const float4*)&S[c][0][p0];
            float4 AX1 = *(const float4*)&S[c][0][p0 + 4];
            float4 AY0 = *(const float4*)&S[c][1][p0];
            float4 AY1 = *(const float4*)&S[c][1][p0 + 4];
            float4 BX0 = *(const float4*)&S[c + CC][0][p0];
            float4 BX1 = *(const float4*)&S[c + CC][0][p0 + 4];
            float4 BY0 = *(const float4*)&S[c + CC][1][p0];
            float4 BY1 = *(const float4*)&S[c + CC][1][p0 + 4];
            float w1x[5] = {AX0.y, AX0.z, AX0.w, AX1.x, AX1.y};
            float w1y[5] = {AY0.y, AY0.z, AY0.w, AY1.x, AY1.y};
            float w2x[5] = {BX0.y, BX0.z, BX0.w, BX1.x, BX1.y};
            float w2y[5] = {BY0.y, BY0.z, BY0.w, BY1.x, BY1.y};
            float4 od, ol1, ol2;
            float* vd = &od.x; float* v1 = &ol1.x; float* v2 = &ol2.x;
#pragma unroll
            for (int k = 0; k < 4; ++k) {
                float d1x = w1x[k + 1] - w1x[k], d1y = w1y[k + 1] - w1y[k];
                float d2x = w2x[k + 1] - w2x[k], d2y = w2y[k + 1] - w2y[k];
                float n1 = fsq(d1x * d1x + d1y * d1y);
                float n2 = fsq(d2x * d2x + d2y * d2y);
                float rx = w1x[k + 1] - w2x[k + 1], ry = w1y[k + 1] - w2y[k + 1];
                float nr = fsq(rx * rx + ry * ry);
                vd[k] = (d1x * d2x + d1y * d2y) * frcp(n1 * n2 + 1e-6f);
                v1[k] = (d1x * rx + d1y * ry) * frcp(n1 * nr + 1e-6f);
                v2[k] = -(d2x * rx + d2y * ry) * frcp(n2 * nr + 1e-6f);
            }
            stnt4(ob + (size_t)(42 + c) * NN,  od);
            stnt4(ob + (size_t)(147 + c) * NN, ol1);
            stnt4(ob + (size_t)(154 + c) * NN, ol2);
        }
    }

    // ---- phase 3: d / dd, j-column blocked per wave-group ----
    const bool lastpt = (N0 + 4 * tl + 4 == NN);
    for (int j = wg; j < 7; j += 4) {
        float4 BX0 = *(const float4*)&S[CC + j][0][p0];
        float4 BX1 = *(const float4*)&S[CC + j][0][p0 + 4];
        float4 BY0 = *(const float4*)&S[CC + j][1][p0];
        float4 BY1 = *(const float4*)&S[CC + j][1][p0 + 4];
        float w2x[5] = {BX0.z, BX0.w, BX1.x, BX1.y, BX1.z};
        float w2y[5] = {BY0.z, BY0.w, BY1.x, BY1.y, BY1.z};
#pragma unroll
        for (int i = 0; i < 7; ++i) {
            int c1 = j - i - 1;
            c1 = (c1 < 0) ? c1 + 7 : c1;
            float4 AX0 = *(const float4*)&S[c1][0][p0];
            float4 AX1 = *(const float4*)&S[c1][0][p0 + 4];
            float4 AY0 = *(const float4*)&S[c1][1][p0];
            float4 AY1 = *(const float4*)&S[c1][1][p0 + 4];
            float w1x[5] = {AX0.z, AX0.w, AX1.x, AX1.y, AX1.z};
            float w1y[5] = {AY0.z, AY0.w, AY1.x, AY1.y, AY1.z};
            float d[5];
#pragma unroll
            for (int p = 0; p < 5; ++p) {
                float ddx = w1x[p] - w2x[p] + 1e-6f;
                float ddy = w1y[p] - w2y[p] + 1e-6f;
                d[p] = fsq(ddx * ddx + ddy * ddy);
            }
            float dd3 = lastpt ? -d[3] : d[4] - d[3];
            const int pair = i * 7 + j;
            stnt4(ob + (size_t)(49 + pair) * NN,
                  make_float4(d[0], d[1], d[2], d[3]));
            stnt4(ob + (size_t)(98 + pair) * NN,
                  make_float4(d[1] - d[0], d[2] - d[1], d[3] - d[2], dd3));
        }
    }
}

extern "C" void kernel_launch(void* const* d_in, const int* in_sizes, int n_in,
                              void* d_out, int out_size, void* d_ws, size_t ws_size,
                              hipStream_t stream) {
    const float* x = (const float*)d_in[0];
    float* out = (float*)d_out;
    dim3 grid(NN / SPAN, 16);
    feat_kernel<<<grid, 256, 0, stream>>>(x, out);
}